// Round 3
// baseline (8276.991 us; speedup 1.0000x reference)
//
#include <hip/hip_runtime.h>
#include <stdint.h>

typedef unsigned int u32;
typedef unsigned short u16;

constexpr int NB  = 4096;   // batch
constexpr int NT  = 56;     // encoder steps
constexpr int NS  = 28;     // decoder steps
constexpr int NH  = 126;    // hidden
constexpr int NHP = 128;    // padded hidden
constexpr int NE  = 20;     // encoder feature
constexpr int ND  = 15;     // decoder feature
constexpr int NX  = 142;    // decoder GRU input = 1 + 15 + 126
constexpr int NXP = 144;    // padded
constexpr int NG  = 378;    // 3*NH

// workspace byte offsets (total ~119.9 MB). bf16 weights, [b][t][h] activations.
constexpr size_t OFF_H    = 0;           // float[4096*128]   h state (padded, pads=0)
constexpr size_t OFF_ENC  = 2097152;     // u16[4096*56*128]  enc_out bf16, [b][t][h]
constexpr size_t OFF_UO   = 60817408;    // u16[4096*56*128]  Uo bf16, [b][t][h]
constexpr size_t OFF_EWIH = 119537664;   // u16[378*32]
constexpr size_t OFF_EWHH = 119561856;   // u16[378*128]
constexpr size_t OFF_DWIH = 119658624;   // u16[378*144]
constexpr size_t OFF_DWHH = 119767488;   // u16[378*128]
constexpr size_t OFF_UW   = 119864256;   // u16[126*128]
constexpr size_t OFF_WL   = 119896512;   // u16[126*128]

__device__ __forceinline__ float fexp2(float x){ return __builtin_amdgcn_exp2f(x); }
__device__ __forceinline__ float frcp (float x){ return __builtin_amdgcn_rcpf(x); }
__device__ __forceinline__ float sigm (float x){ return frcp(1.f + fexp2(-1.4426950408889634f * x)); }
__device__ __forceinline__ float ftanh(float x){ return 1.f - 2.f * frcp(1.f + fexp2(2.8853900817779268f * x)); }
__device__ __forceinline__ float asf(u32 u){ union { u32 i; float f; } v; v.i = u; return v.f; }
__device__ __forceinline__ u32 f2bf(float f){ union { float f; u32 i; } v; v.f = f;
  return (v.i + 0x7fffu + ((v.i >> 16) & 1u)) >> 16; }
__device__ __forceinline__ u32 packbf(float lo, float hi){ return f2bf(lo) | (f2bf(hi) << 16); }
__device__ __forceinline__ float bflo(u32 q){ return asf(q << 16); }
__device__ __forceinline__ float bfhi(u32 q){ return asf(q & 0xffff0000u); }

// wave-local "sync": compiler fence only (a wave is one instruction stream —
// no hardware barrier needed, just stop the compiler reordering LDS ops).
__device__ __forceinline__ void wsync(){
  __builtin_amdgcn_fence(__ATOMIC_ACQ_REL, "workgroup");
  __builtin_amdgcn_wave_barrier();
}

// 8 bf16 weights (uint4) * 8 fp32 activations -> accumulate
__device__ __forceinline__ void acc8(float& a, const uint4 w,
                                     const float4 h0, const float4 h1){
  a += bflo(w.x) * h0.x; a += bfhi(w.x) * h0.y;
  a += bflo(w.y) * h0.z; a += bfhi(w.y) * h0.w;
  a += bflo(w.z) * h1.x; a += bfhi(w.z) * h1.y;
  a += bflo(w.w) * h1.z; a += bfhi(w.w) * h1.w;
}

// ---------------- weight repack: fp32 -> bf16, zero-padded rows ----------------
__global__ void k_prep(const float* __restrict__ eWih, const float* __restrict__ eWhh,
                       const float* __restrict__ dWih, const float* __restrict__ dWhh,
                       const float* __restrict__ UW,   const float* __restrict__ Wl,
                       char* __restrict__ ws)
{
  u16* oEI = (u16*)(ws + OFF_EWIH);
  u16* oEH = (u16*)(ws + OFF_EWHH);
  u16* oDI = (u16*)(ws + OFF_DWIH);
  u16* oDH = (u16*)(ws + OFF_DWHH);
  u16* oU  = (u16*)(ws + OFF_UW);
  u16* oW  = (u16*)(ws + OFF_WL);
  const int nEI = NG*32, nEH = NG*128, nDI = NG*144, nDH = NG*128, nU = NH*128;
  const int total = nEI + nEH + nDI + nDH + nU + nU;
  for (int i = blockIdx.x * 256 + threadIdx.x; i < total; i += gridDim.x * 256) {
    int idx = i;
    if (idx < nEI){ int r=idx>>5,  c=idx&31;   oEI[idx]=(u16)((c<NE)?f2bf(eWih[r*NE+c]):0); continue; } idx-=nEI;
    if (idx < nEH){ int r=idx>>7,  c=idx&127;  oEH[idx]=(u16)((c<NH)?f2bf(eWhh[r*NH+c]):0); continue; } idx-=nEH;
    if (idx < nDI){ int r=idx/144, c=idx%144;  oDI[idx]=(u16)((c<NX)?f2bf(dWih[r*NX+c]):0); continue; } idx-=nDI;
    if (idx < nDH){ int r=idx>>7,  c=idx&127;  oDH[idx]=(u16)((c<NH)?f2bf(dWhh[r*NH+c]):0); continue; } idx-=nDH;
    if (idx < nU ){ int r=idx>>7,  c=idx&127;  oU [idx]=(u16)((c<NH)?f2bf(UW  [r*NH+c]):0); continue; } idx-=nU;
    { int r=idx>>7, c=idx&127; oW[idx]=(u16)((c<NH)?f2bf(Wl[r*NH+c]):0); }
  }
}

// ---------------- init MLP: h0 = relu(ann@W1^T+b1)@W2^T+b2 (padded store) ----------------
__global__ __launch_bounds__(256) void k_mlp(
    const float* __restrict__ ann, const float* __restrict__ W1, const float* __restrict__ b1,
    const float* __restrict__ W2, const float* __restrict__ b2, float* __restrict__ hstate)
{
  __shared__ float anns[32][33];
  __shared__ float t1s[32][101];
  const int tid = threadIdx.x;
  const int b0 = blockIdx.x * 32;
  for (int i = tid; i < 32 * 30; i += 256)
    anns[i / 30][i % 30] = ann[(b0 + i / 30) * 30 + (i % 30)];
  __syncthreads();
  const int b = tid & 31, rg = tid >> 5;
  for (int m = rg; m < 96; m += 8) {
    float a = b1[m];
    for (int k = 0; k < 30; ++k) a += W1[m * 30 + k] * anns[b][k];
    t1s[b][m] = fmaxf(a, 0.f);
  }
  __syncthreads();
  for (int j = rg; j < NHP; j += 8) {
    float a = 0.f;
    if (j < NH) {
      a = b2[j];
      for (int k = 0; k < 96; ++k) a += W2[j * 96 + k] * t1s[b][k];
    }
    hstate[(b0 + b) * NHP + j] = a;
  }
}

// ---------------- encoder: one wave = one batch row; no __syncthreads ----------------
__global__ __launch_bounds__(256, 4) void k_enc(
    const float* __restrict__ xenc, const u16* __restrict__ WihB,
    const float* __restrict__ bih, const float* __restrict__ bhh,
    const u16* __restrict__ WhhB, const u16* __restrict__ UWb,
    const float* __restrict__ Ub, float* __restrict__ hstate,
    u16* __restrict__ encB, u16* __restrict__ uoB)
{
  __shared__ __align__(16) float hS[4][2][NHP];
  const int tid = threadIdx.x, wid = tid >> 6, l = tid & 63;
  const int b = blockIdx.x * 4 + wid;
  const int j0 = 2 * l;
  const int jr0 = (j0     < NH) ? j0     : NH - 1;
  const int jr1 = (j0 + 1 < NH) ? j0 + 1 : NH - 1;
  const bool act = (j0 < NH);

  const float bir0=bih[jr0], bir1=bih[jr1], biz0=bih[NH+jr0], biz1=bih[NH+jr1],
              bin0=bih[2*NH+jr0], bin1=bih[2*NH+jr1];
  const float bhr0=bhh[jr0], bhr1=bhh[jr1], bhz0=bhh[NH+jr0], bhz1=bhh[NH+jr1],
              bhn0=bhh[2*NH+jr0], bhn1=bhh[2*NH+jr1];
  const float ub0=Ub[jr0], ub1=Ub[jr1];

  const u16 *wxr0=WihB+jr0*32,        *wxr1=WihB+jr1*32,
            *wxz0=WihB+(NH+jr0)*32,   *wxz1=WihB+(NH+jr1)*32,
            *wxn0=WihB+(2*NH+jr0)*32, *wxn1=WihB+(2*NH+jr1)*32;
  const u16 *whr0=WhhB+jr0*NHP,        *whr1=WhhB+jr1*NHP,
            *whz0=WhhB+(NH+jr0)*NHP,   *whz1=WhhB+(NH+jr1)*NHP,
            *whn0=WhhB+(2*NH+jr0)*NHP, *whn1=WhhB+(2*NH+jr1)*NHP;
  const u16 *uw0=UWb+jr0*NHP, *uw1=UWb+jr1*NHP;

  { const float2 h2i = *(const float2*)&hstate[b * NHP + j0];   // pads are 0
    hS[wid][0][j0] = h2i.x; hS[wid][0][j0 + 1] = h2i.y;
    if (l == 63) { hS[wid][1][126] = 0.f; hS[wid][1][127] = 0.f; } }
  wsync();

  float x[24]; x[20]=x[21]=x[22]=x[23]=0.f;

  for (int t = 0; t < NT; ++t) {
    { const float4* xp = (const float4*)&xenc[((size_t)t * NB + b) * NE];
      *(float4*)&x[0]=xp[0]; *(float4*)&x[4]=xp[1]; *(float4*)&x[8]=xp[2];
      *(float4*)&x[12]=xp[3]; *(float4*)&x[16]=xp[4]; }
    const float* hc = hS[wid][t & 1];
    float*       hw = hS[wid][(t + 1) & 1];

    float ar0=bir0, ar1=bir1, az0=biz0, az1=biz1, an0=bin0, an1=bin1;
    float hrr0=bhr0, hrr1=bhr1, hzz0=bhz0, hzz1=bhz1, hnn0=bhn0, hnn1=bhn1;
#pragma unroll
    for (int k = 0; k < 24; k += 8) {
      const float4 x0 = *(const float4*)&x[k], x1 = *(const float4*)&x[k + 4];
      acc8(ar0, *(const uint4*)&wxr0[k], x0, x1);
      acc8(ar1, *(const uint4*)&wxr1[k], x0, x1);
      acc8(az0, *(const uint4*)&wxz0[k], x0, x1);
      acc8(az1, *(const uint4*)&wxz1[k], x0, x1);
      acc8(an0, *(const uint4*)&wxn0[k], x0, x1);
      acc8(an1, *(const uint4*)&wxn1[k], x0, x1);
    }
#pragma unroll 4
    for (int k = 0; k < NHP; k += 8) {
      const float4 h0 = *(const float4*)&hc[k], h1 = *(const float4*)&hc[k + 4];
      acc8(hrr0, *(const uint4*)&whr0[k], h0, h1);
      acc8(hrr1, *(const uint4*)&whr1[k], h0, h1);
      acc8(hzz0, *(const uint4*)&whz0[k], h0, h1);
      acc8(hzz1, *(const uint4*)&whz1[k], h0, h1);
      acc8(hnn0, *(const uint4*)&whn0[k], h0, h1);
      acc8(hnn1, *(const uint4*)&whn1[k], h0, h1);
    }
    const float r0 = sigm(ar0 + hrr0), r1 = sigm(ar1 + hrr1);
    const float z0 = sigm(az0 + hzz0), z1 = sigm(az1 + hzz1);
    const float n0 = ftanh(an0 + r0 * hnn0), n1 = ftanh(an1 + r1 * hnn1);
    const float h2v0 = (1.f - z0) * n0 + z0 * hc[j0];
    const float h2v1 = (1.f - z1) * n1 + z1 * hc[j0 + 1];
    if (act) { hw[j0] = h2v0; hw[j0 + 1] = h2v1; }   // pads stay 0 forever
    wsync();

    float uo0 = ub0, uo1 = ub1;
#pragma unroll 4
    for (int k = 0; k < NHP; k += 8) {
      const float4 h0 = *(const float4*)&hw[k], h1 = *(const float4*)&hw[k + 4];
      acc8(uo0, *(const uint4*)&uw0[k], h0, h1);
      acc8(uo1, *(const uint4*)&uw1[k], h0, h1);
    }
    const int base = (b * NT + t) * NHP + j0;
    *(u32*)&encB[base] = act ? packbf(h2v0, h2v1) : 0u;
    *(u32*)&uoB [base] = act ? packbf(uo0, uo1)   : 0u;
    if (t == NT - 1) {
      float2 st; st.x = act ? h2v0 : 0.f; st.y = act ? h2v1 : 0.f;
      *(float2*)&hstate[b * NHP + j0] = st;
    }
  }
}

// ---------------- decoder: one wave = one batch row; no per-step barriers ----------------
__global__ __launch_bounds__(256, 4) void k_dec(
    const float* __restrict__ xdec, const float* __restrict__ xenc,
    const u16* __restrict__ WihB, const u16* __restrict__ WhhB,
    const float* __restrict__ bih, const float* __restrict__ bhh,
    const u16* __restrict__ WlB, const float* __restrict__ Wlb,
    const float* __restrict__ Vw, const float* __restrict__ Vb,
    const float* __restrict__ how, const float* __restrict__ hob,
    const float* __restrict__ hstate,
    const u16* __restrict__ encB, const u16* __restrict__ uoB,
    float* __restrict__ out)
{
  __shared__ __align__(16) float hS[4][2][NHP];
  __shared__ __align__(16) float WhS[4][NHP];
  __shared__ __align__(16) float xS[4][NXP];
  __shared__ __align__(16) float alS[4][64];
  __shared__ __align__(16) float Vs[NHP];
  const int tid = threadIdx.x, wid = tid >> 6, l = tid & 63;
  const int b = blockIdx.x * 4 + wid;
  const int j0 = 2 * l;
  const int jr0 = (j0     < NH) ? j0     : NH - 1;
  const int jr1 = (j0 + 1 < NH) ? j0 + 1 : NH - 1;
  const bool act = (j0 < NH);

  const float bir0=bih[jr0], bir1=bih[jr1], biz0=bih[NH+jr0], biz1=bih[NH+jr1],
              bin0=bih[2*NH+jr0], bin1=bih[2*NH+jr1];
  const float bhr0=bhh[jr0], bhr1=bhh[jr1], bhz0=bhh[NH+jr0], bhz1=bhh[NH+jr1],
              bhn0=bhh[2*NH+jr0], bhn1=bhh[2*NH+jr1];
  const float wlb0=Wlb[jr0], wlb1=Wlb[jr1];
  const float how0 = act ? how[j0] : 0.f;
  const float how1 = (j0 + 1 < NH) ? how[j0 + 1] : 0.f;
  const float vb0 = Vb[0], hob0 = hob[0];

  const u16 *wl0=WlB+jr0*NHP, *wl1=WlB+jr1*NHP;
  const u16 *dxr0=WihB+jr0*NXP,        *dxr1=WihB+jr1*NXP,
            *dxz0=WihB+(NH+jr0)*NXP,   *dxz1=WihB+(NH+jr1)*NXP,
            *dxn0=WihB+(2*NH+jr0)*NXP, *dxn1=WihB+(2*NH+jr1)*NXP;
  const u16 *dhr0=WhhB+jr0*NHP,        *dhr1=WhhB+jr1*NHP,
            *dhz0=WhhB+(NH+jr0)*NHP,   *dhz1=WhhB+(NH+jr1)*NHP,
            *dhn0=WhhB+(2*NH+jr0)*NHP, *dhn1=WhhB+(2*NH+jr1)*NHP;

  if (tid < NHP) Vs[tid] = (tid < NH) ? Vw[tid] : 0.f;
  { const float2 h2i = *(const float2*)&hstate[b * NHP + j0];
    hS[wid][0][j0] = h2i.x; hS[wid][0][j0 + 1] = h2i.y;
    if (l == 63) { hS[wid][1][126] = 0.f; hS[wid][1][127] = 0.f;
                   xS[wid][142] = 0.f; xS[wid][143] = 0.f; } }
  float prev = xenc[((size_t)(NT - 1) * NB + b) * NE];   // gt0, all lanes
  __syncthreads();   // once, for block-shared Vs

  const u16* uorow = uoB + (size_t)(b * NT + ((l < NT) ? l : NT - 1)) * NHP;
  const u16* erow  = encB + (size_t)b * NT * NHP + j0;

  for (int s = 0; s < NS; ++s) {
    const float* hc = hS[wid][s & 1];
    float*       hx = hS[wid][(s + 1) & 1];

    // p1: Wh = h @ Wl^T + Wlb ; stage prev + dec_x into x buffer
    float wa0 = wlb0, wa1 = wlb1;
#pragma unroll 4
    for (int k = 0; k < NHP; k += 8) {
      const float4 h0 = *(const float4*)&hc[k], h1 = *(const float4*)&hc[k + 4];
      acc8(wa0, *(const uint4*)&wl0[k], h0, h1);
      acc8(wa1, *(const uint4*)&wl1[k], h0, h1);
    }
    WhS[wid][j0] = wa0; WhS[wid][j0 + 1] = wa1;   // lane63 dups are harmless (V pad=0)
    if (l < ND)  xS[wid][1 + l] = xdec[((size_t)s * NB + b) * ND + l];
    if (l == ND) xS[wid][0] = prev;
    wsync();

    // p2: lane t: score[t] = V . tanh(Uo[b][t] + Wh) + Vb
    float acc = 0.f;
#pragma unroll 2
    for (int k = 0; k < NHP; k += 8) {
      const uint4 q = *(const uint4*)&uorow[k];
      const float4 w0 = *(const float4*)&WhS[wid][k], w1 = *(const float4*)&WhS[wid][k + 4];
      const float4 v0 = *(const float4*)&Vs[k],       v1 = *(const float4*)&Vs[k + 4];
      acc += ftanh(bflo(q.x) + w0.x) * v0.x + ftanh(bfhi(q.x) + w0.y) * v0.y
           + ftanh(bflo(q.y) + w0.z) * v0.z + ftanh(bfhi(q.y) + w0.w) * v0.w
           + ftanh(bflo(q.z) + w1.x) * v1.x + ftanh(bfhi(q.z) + w1.y) * v1.y
           + ftanh(bflo(q.w) + w1.z) * v1.z + ftanh(bfhi(q.w) + w1.w) * v1.w;
    }
    const float sc = (l < NT) ? acc + vb0 : -1e30f;
    // softmax across the wave (lanes 56..63 contribute 0)
    float m = sc;
#pragma unroll
    for (int mm = 1; mm < 64; mm <<= 1) m = fmaxf(m, __shfl_xor(m, mm, 64));
    const float e = (l < NT) ? fexp2(1.4426950408889634f * (sc - m)) : 0.f;
    float Z = e;
#pragma unroll
    for (int mm = 1; mm < 64; mm <<= 1) Z += __shfl_xor(Z, mm, 64);
    alS[wid][l] = e * frcp(Z);
    wsync();

    // p3: attn_j = sum_t alpha[t] * enc[b][t][j]  (coalesced u32 per t)
    float a0 = 0.f, a1 = 0.f;
#pragma unroll 2
    for (int t = 0; t < NT; t += 4) {
      const float4 alv = *(const float4*)&alS[wid][t];
      const u32 q0 = *(const u32*)&erow[(t    ) * NHP];
      const u32 q1 = *(const u32*)&erow[(t + 1) * NHP];
      const u32 q2 = *(const u32*)&erow[(t + 2) * NHP];
      const u32 q3 = *(const u32*)&erow[(t + 3) * NHP];
      a0 += alv.x * bflo(q0) + alv.y * bflo(q1) + alv.z * bflo(q2) + alv.w * bflo(q3);
      a1 += alv.x * bfhi(q0) + alv.y * bfhi(q1) + alv.z * bfhi(q2) + alv.w * bfhi(q3);
    }
    if (act) { xS[wid][16 + j0] = a0; xS[wid][16 + j0 + 1] = a1; }
    wsync();

    // p4: GRU step on x = [prev, dec_x, attn]
    float ar0=bir0, ar1=bir1, az0=biz0, az1=biz1, an0=bin0, an1=bin1;
    float hrr0=bhr0, hrr1=bhr1, hzz0=bhz0, hzz1=bhz1, hnn0=bhn0, hnn1=bhn1;
#pragma unroll 2
    for (int k = 0; k < NXP; k += 8) {
      const float4 x0 = *(const float4*)&xS[wid][k], x1 = *(const float4*)&xS[wid][k + 4];
      acc8(ar0, *(const uint4*)&dxr0[k], x0, x1);
      acc8(ar1, *(const uint4*)&dxr1[k], x0, x1);
      acc8(az0, *(const uint4*)&dxz0[k], x0, x1);
      acc8(az1, *(const uint4*)&dxz1[k], x0, x1);
      acc8(an0, *(const uint4*)&dxn0[k], x0, x1);
      acc8(an1, *(const uint4*)&dxn1[k], x0, x1);
    }
#pragma unroll 2
    for (int k = 0; k < NHP; k += 8) {
      const float4 h0 = *(const float4*)&hc[k], h1 = *(const float4*)&hc[k + 4];
      acc8(hrr0, *(const uint4*)&dhr0[k], h0, h1);
      acc8(hrr1, *(const uint4*)&dhr1[k], h0, h1);
      acc8(hzz0, *(const uint4*)&dhz0[k], h0, h1);
      acc8(hzz1, *(const uint4*)&dhz1[k], h0, h1);
      acc8(hnn0, *(const uint4*)&dhn0[k], h0, h1);
      acc8(hnn1, *(const uint4*)&dhn1[k], h0, h1);
    }
    const float r0 = sigm(ar0 + hrr0), r1 = sigm(ar1 + hrr1);
    const float z0 = sigm(az0 + hzz0), z1 = sigm(az1 + hzz1);
    const float n0 = ftanh(an0 + r0 * hnn0), n1 = ftanh(an1 + r1 * hnn1);
    const float h2v0 = (1.f - z0) * n0 + z0 * hc[j0];
    const float h2v1 = (1.f - z1) * n1 + z1 * hc[j0 + 1];
    if (act) { hx[j0] = h2v0; hx[j0 + 1] = h2v1; }

    // p5: out = h2 . h2o + b — butterfly leaves the sum in every lane
    float o = h2v0 * how0 + h2v1 * how1;
#pragma unroll
    for (int mm = 1; mm < 64; mm <<= 1) o += __shfl_xor(o, mm, 64);
    prev = o + hob0;
    if (l == 0) out[s * NB + b] = prev;
    wsync();
  }
}

extern "C" void kernel_launch(void* const* d_in, const int* in_sizes, int n_in,
                              void* d_out, int out_size, void* d_ws, size_t ws_size,
                              hipStream_t stream)
{
  const float* ann   = (const float*)d_in[0];
  const float* xenc  = (const float*)d_in[1];
  const float* xdec  = (const float*)d_in[2];
  const float* W1    = (const float*)d_in[3];
  const float* b1    = (const float*)d_in[4];
  const float* W2    = (const float*)d_in[5];
  const float* b2    = (const float*)d_in[6];
  const float* eWih  = (const float*)d_in[7];
  const float* eWhh  = (const float*)d_in[8];
  const float* ebih  = (const float*)d_in[9];
  const float* ebhh  = (const float*)d_in[10];
  const float* dWih  = (const float*)d_in[11];
  const float* dWhh  = (const float*)d_in[12];
  const float* dbih  = (const float*)d_in[13];
  const float* dbhh  = (const float*)d_in[14];
  const float* UW    = (const float*)d_in[15];
  const float* Ubias = (const float*)d_in[16];
  const float* Wl    = (const float*)d_in[17];
  const float* Wlb   = (const float*)d_in[18];
  const float* Vw    = (const float*)d_in[19];
  const float* Vb    = (const float*)d_in[20];
  const float* how   = (const float*)d_in[21];
  const float* hob   = (const float*)d_in[22];

  char* ws = (char*)d_ws;
  float* hstate = (float*)(ws + OFF_H);
  u16*   encB   = (u16*)(ws + OFF_ENC);
  u16*   uoB    = (u16*)(ws + OFF_UO);
  const u16* pEWih = (const u16*)(ws + OFF_EWIH);
  const u16* pEWhh = (const u16*)(ws + OFF_EWHH);
  const u16* pDWih = (const u16*)(ws + OFF_DWIH);
  const u16* pDWhh = (const u16*)(ws + OFF_DWHH);
  const u16* pUW   = (const u16*)(ws + OFF_UW);
  const u16* pWl   = (const u16*)(ws + OFF_WL);

  k_prep<<<764, 256, 0, stream>>>(eWih, eWhh, dWih, dWhh, UW, Wl, ws);
  k_mlp <<<128, 256, 0, stream>>>(ann, W1, b1, W2, b2, hstate);
  k_enc <<<NB / 4, 256, 0, stream>>>(xenc, pEWih, ebih, ebhh, pEWhh, pUW, Ubias,
                                     hstate, encB, uoB);
  k_dec <<<NB / 4, 256, 0, stream>>>(xdec, xenc, pDWih, pDWhh, dbih, dbhh,
                                     pWl, Wlb, Vw, Vb, how, hob, hstate,
                                     encB, uoB, (float*)d_out);
}

// Round 4
// 1308.354 us; speedup vs baseline: 6.3263x; 6.3263x over previous
//
#include <hip/hip_runtime.h>
#include <stdint.h>

typedef unsigned int u32;
typedef unsigned short u16;
typedef _Float16 f16;
typedef _Float16 f16x8 __attribute__((ext_vector_type(8)));
typedef _Float16 f16x4 __attribute__((ext_vector_type(4)));
typedef float f32x4 __attribute__((ext_vector_type(4)));

constexpr int NB = 4096;   // batch
constexpr int NT = 56;     // encoder steps
constexpr int NS = 28;     // decoder steps
constexpr int NH = 126;    // hidden
constexpr int NHP = 128;

// workspace offsets (bytes), total ~119.9 MB
constexpr size_t OFF_H    = 0;                    // f32[4096*128] h state (pads 0)
constexpr size_t OFF_ENC  = 2097152;              // f16[4096*56*128] enc_out [b][t][h]
constexpr size_t OFF_UO   = OFF_ENC + 58720256;   // f16[4096*56*128] Uo      [b][t][h]
constexpr size_t OFF_WENC = OFF_UO + 58720256;    // f16[384*160]  enc gates [x(20)+pad|h(128)]
constexpr size_t OFF_WDEC = OFF_WENC + 122880;    // f16[384*288]  dec gates [head(16)+pad|attn(128)|h(128)]
constexpr size_t OFF_WL   = OFF_WDEC + 221184;    // f16[128*128]  Wl
constexpr size_t OFF_UW   = OFF_WL + 32768;       // f16[128*128]  U_W

__device__ __forceinline__ float fexp2(float x){ return __builtin_amdgcn_exp2f(x); }
__device__ __forceinline__ float frcp (float x){ return __builtin_amdgcn_rcpf(x); }
__device__ __forceinline__ float sigm (float x){ return frcp(1.f + fexp2(-1.4426950408889634f * x)); }
__device__ __forceinline__ float ftanh(float x){ return 1.f - 2.f * frcp(1.f + fexp2(2.8853900817779268f * x)); }

// ---------------- weight repack: fp32 -> fp16, MFMA-friendly padded K-layouts ----------------
__global__ void k_prep(const float* __restrict__ eWih, const float* __restrict__ eWhh,
                       const float* __restrict__ dWih, const float* __restrict__ dWhh,
                       const float* __restrict__ UW,   const float* __restrict__ Wl,
                       char* __restrict__ ws)
{
  f16* wenc = (f16*)(ws + OFF_WENC);
  f16* wdec = (f16*)(ws + OFF_WDEC);
  f16* wl   = (f16*)(ws + OFF_WL);
  f16* uw   = (f16*)(ws + OFF_UW);
  const int nE = 384 * 160, nD = 384 * 288, nW = 128 * 128;
  const int total = nE + nD + nW + nW;
  for (int i = blockIdx.x * 256 + threadIdx.x; i < total; i += gridDim.x * 256) {
    int idx = i;
    if (idx < nE) {
      const int r = idx / 160, c = idx % 160;
      float v = 0.f;
      if (r < 378) {
        if (c < 20) v = eWih[r * 20 + c];
        else if (c >= 32 && c < 158) v = eWhh[r * 126 + (c - 32)];
      }
      wenc[idx] = (f16)v; continue;
    }
    idx -= nE;
    if (idx < nD) {
      const int r = idx / 288, c = idx % 288;
      float v = 0.f;
      if (r < 378) {
        if (c < 16) v = dWih[r * 142 + c];                       // [prev, dec_x(15)]
        else if (c >= 32 && c < 158) v = dWih[r * 142 + 16 + (c - 32)];  // attn
        else if (c >= 160 && c < 286) v = dWhh[r * 126 + (c - 160)];     // h
      }
      wdec[idx] = (f16)v; continue;
    }
    idx -= nD;
    if (idx < nW) {
      const int r = idx >> 7, c = idx & 127;
      wl[idx] = (f16)((r < 126 && c < 126) ? Wl[r * 126 + c] : 0.f);
      continue;
    }
    idx -= nW;
    { const int r = idx >> 7, c = idx & 127;
      uw[idx] = (f16)((r < 126 && c < 126) ? UW[r * 126 + c] : 0.f); }
  }
}

// ---------------- init MLP: h0 = relu(ann@W1^T+b1)@W2^T+b2 (padded fp32 store) ----------------
__global__ __launch_bounds__(256) void k_mlp(
    const float* __restrict__ ann, const float* __restrict__ W1, const float* __restrict__ b1,
    const float* __restrict__ W2, const float* __restrict__ b2, float* __restrict__ hstate)
{
  __shared__ float anns[32][33];
  __shared__ float t1s[32][101];
  const int tid = threadIdx.x;
  const int b0 = blockIdx.x * 32;
  for (int i = tid; i < 32 * 30; i += 256)
    anns[i / 30][i % 30] = ann[(b0 + i / 30) * 30 + (i % 30)];
  __syncthreads();
  const int b = tid & 31, rg = tid >> 5;
  for (int m = rg; m < 96; m += 8) {
    float a = b1[m];
    for (int k = 0; k < 30; ++k) a += W1[m * 30 + k] * anns[b][k];
    t1s[b][m] = fmaxf(a, 0.f);
  }
  __syncthreads();
  for (int j = rg; j < NHP; j += 8) {
    float a = 0.f;
    if (j < NH) {
      a = b2[j];
      for (int k = 0; k < 96; ++k) a += W2[j * 96 + k] * t1s[b][k];
    }
    hstate[(b0 + b) * NHP + j] = a;
  }
}

// ---------------- encoder: MFMA, register-resident weights, M=16 b/block ----------------
// 512 thr = 8 waves; wave w owns gate cols [16w,16w+16). A: m=lane&15,k=quad*8+i;
// B: n=lane&15,k=quad*8+i; C/D: col=lane&15,row=quad*4+reg.
__global__ __launch_bounds__(512) void k_enc(
    const float* __restrict__ xenc, const f16* __restrict__ Wenc,
    const f16* __restrict__ Uw,
    const float* __restrict__ bih, const float* __restrict__ bhh,
    const float* __restrict__ Ub,
    float* __restrict__ hstate, f16* __restrict__ encO, f16* __restrict__ uoO)
{
  __shared__ f16 av[16][168];   // [b][ x(20)+pad(12) | h(128) ], stride 168 (bank-spread)
  const int tid = threadIdx.x;
  const int wid = tid >> 6, l = tid & 63, quad = l >> 4, col = l & 15;
  const int b0 = blockIdx.x * 16;
  const int jb = wid * 16, j = jb + col;
  const bool valid = j < NH;
  const int jc = valid ? j : NH - 1;

  const float br  = bih[jc]        + bhh[jc];
  const float bz  = bih[NH + jc]   + bhh[NH + jc];
  const float bnx = bih[2*NH + jc];
  const float bnh = bhh[2*NH + jc];
  const float ub  = Ub[jc];

  // B-fragments, loaded once (rows >=126 of a section read the next section ->
  // garbage, but only for pad columns j=126,127 which are discarded)
  f16x8 rB[5], zB[5], nxB, nhB[4], uB[4];
  {
    const int ko = quad * 8, rr = jb + col;
#pragma unroll
    for (int kt = 0; kt < 5; ++kt) {
      rB[kt] = *(const f16x8*)&Wenc[rr * 160 + kt * 32 + ko];
      zB[kt] = *(const f16x8*)&Wenc[(NH + rr) * 160 + kt * 32 + ko];
    }
    nxB = *(const f16x8*)&Wenc[(2*NH + rr) * 160 + ko];
#pragma unroll
    for (int kt = 0; kt < 4; ++kt) {
      nhB[kt] = *(const f16x8*)&Wenc[(2*NH + rr) * 160 + 32 + kt * 32 + ko];
      uB[kt]  = *(const f16x8*)&Uw[rr * 128 + kt * 32 + ko];
    }
  }

  { // stage h0 (fp32->fp16), zero x-pad cols 20..31
    const int bb = tid >> 5, c4 = (tid & 31) * 4;
    const float4 hv = *(const float4*)&hstate[(b0 + bb) * NHP + c4];
    av[bb][32 + c4]     = (f16)hv.x; av[bb][32 + c4 + 1] = (f16)hv.y;
    av[bb][32 + c4 + 2] = (f16)hv.z; av[bb][32 + c4 + 3] = (f16)hv.w;
  }
  if (tid < 192) { const int bb = tid / 12, p = tid % 12; av[bb][20 + p] = (f16)0.f; }
  __syncthreads();

  const int m = col, ko = quad * 8;
  for (int t = 0; t < NT; ++t) {
    if (tid < 320) {
      const int bb = tid / 20, e = tid % 20;
      av[bb][e] = (f16)xenc[((size_t)t * NB + b0 + bb) * 20 + e];
    }
    __syncthreads();                       // B1: x staged, h' of prev step done
    f16x8 A[5];
#pragma unroll
    for (int kt = 0; kt < 5; ++kt) A[kt] = *(const f16x8*)&av[m][kt * 32 + ko];
    __syncthreads();                       // B2: all A-loads complete before h'-writes

    f32x4 Cr = {br, br, br, br}, Cz = {bz, bz, bz, bz};
    f32x4 Cnx = {bnx, bnx, bnx, bnx}, Cnh = {bnh, bnh, bnh, bnh};
#pragma unroll
    for (int kt = 0; kt < 5; ++kt) {
      Cr = __builtin_amdgcn_mfma_f32_16x16x32_f16(A[kt], rB[kt], Cr, 0, 0, 0);
      Cz = __builtin_amdgcn_mfma_f32_16x16x32_f16(A[kt], zB[kt], Cz, 0, 0, 0);
    }
    Cnx = __builtin_amdgcn_mfma_f32_16x16x32_f16(A[0], nxB, Cnx, 0, 0, 0);
#pragma unroll
    for (int kt = 0; kt < 4; ++kt)
      Cnh = __builtin_amdgcn_mfma_f32_16x16x32_f16(A[kt + 1], nhB[kt], Cnh, 0, 0, 0);

    float hv4[4];
#pragma unroll
    for (int c = 0; c < 4; ++c) {
      const int bb = quad * 4 + c;
      const float hold = (float)av[bb][32 + j];
      const float r = sigm(Cr[c]), z = sigm(Cz[c]);
      const float n = ftanh(Cnx[c] + r * Cnh[c]);
      hv4[c] = (1.f - z) * n + z * hold;
    }
#pragma unroll
    for (int c = 0; c < 4; ++c) {
      const int bb = quad * 4 + c;
      const f16 hs = valid ? (f16)hv4[c] : (f16)0.f;
      if (valid) av[bb][32 + j] = hs;
      encO[((size_t)(b0 + bb) * NT + t) * 128 + j] = hs;
    }
    if (t == NT - 1 && valid) {
#pragma unroll
      for (int c = 0; c < 4; ++c)
        hstate[(b0 + quad * 4 + c) * NHP + j] = hv4[c];
    }
    __syncthreads();                       // B3: h' complete

    f16x8 Ah[4];
#pragma unroll
    for (int kt = 0; kt < 4; ++kt) Ah[kt] = *(const f16x8*)&av[m][32 + kt * 32 + ko];
    f32x4 Cu = {ub, ub, ub, ub};
#pragma unroll
    for (int kt = 0; kt < 4; ++kt)
      Cu = __builtin_amdgcn_mfma_f32_16x16x32_f16(Ah[kt], uB[kt], Cu, 0, 0, 0);
#pragma unroll
    for (int c = 0; c < 4; ++c)
      uoO[((size_t)(b0 + quad * 4 + c) * NT + t) * 128 + j] = valid ? (f16)Cu[c] : (f16)0.f;
  }
}

// ---------------- decoder: MFMA gates + streaming attention; M=16 b/block ----------------
__global__ __launch_bounds__(512) void k_dec(
    const float* __restrict__ xdec, const float* __restrict__ xenc,
    const f16* __restrict__ Wdec, const f16* __restrict__ WlW,
    const float* __restrict__ bih, const float* __restrict__ bhh,
    const float* __restrict__ Wlb, const float* __restrict__ Vw,
    const float* __restrict__ Vb, const float* __restrict__ how,
    const float* __restrict__ hob, const float* __restrict__ hstate,
    const f16* __restrict__ encO, const f16* __restrict__ uoO,
    float* __restrict__ out)
{
  __shared__ f16 av[16][296];      // [b][ head(16)+pad(16) | attn(128) | h(128) ]
  __shared__ float WhS[16][132];
  __shared__ float scS[16][64];
  __shared__ float prevS[16];
  const int tid = threadIdx.x;
  const int wid = tid >> 6, l = tid & 63, quad = l >> 4, col = l & 15;
  const int b0 = blockIdx.x * 16;
  const int jb = wid * 16, j = jb + col;
  const bool valid = j < NH;
  const int jc = valid ? j : NH - 1;

  const float br  = bih[jc]        + bhh[jc];
  const float bz  = bih[NH + jc]   + bhh[NH + jc];
  const float bnx = bih[2*NH + jc];
  const float bnh = bhh[2*NH + jc];
  const float wb  = Wlb[jc];
  const float vb0 = Vb[0], hob0 = hob[0];

  f16x8 rB[9], zB[9], nxB[5], nhB[4], wlB[4];
  {
    const int ko = quad * 8, rr = jb + col;
#pragma unroll
    for (int kt = 0; kt < 9; ++kt) {
      rB[kt] = *(const f16x8*)&Wdec[rr * 288 + kt * 32 + ko];
      zB[kt] = *(const f16x8*)&Wdec[(NH + rr) * 288 + kt * 32 + ko];
    }
#pragma unroll
    for (int kt = 0; kt < 5; ++kt)
      nxB[kt] = *(const f16x8*)&Wdec[(2*NH + rr) * 288 + kt * 32 + ko];
#pragma unroll
    for (int kt = 0; kt < 4; ++kt) {
      nhB[kt] = *(const f16x8*)&Wdec[(2*NH + rr) * 288 + 160 + kt * 32 + ko];
      wlB[kt] = *(const f16x8*)&WlW[rr * 128 + kt * 32 + ko];
    }
  }

  // score/attn/out thread constants: group g of 8 lanes, sub = lane-in-group
  const int g = tid >> 3, sub = tid & 7;
  const int sb = g & 15;                    // fixed batch row for score phase
  float vreg[16], howreg[16];
#pragma unroll
  for (int i = 0; i < 16; ++i) {
    const int jj = sub * 16 + i;
    vreg[i]   = (jj < NH) ? Vw[jj]  : 0.f;
    howreg[i] = (jj < NH) ? how[jj] : 0.f;
  }

  { // stage h0; zero pads (head-pad 16..31, attn-pad 158..159, h-pad 286..287)
    const int bb = tid >> 5, c4 = (tid & 31) * 4;
    const float4 hv = *(const float4*)&hstate[(b0 + bb) * NHP + c4];
    av[bb][160 + c4]     = (f16)hv.x; av[bb][160 + c4 + 1] = (f16)hv.y;
    av[bb][160 + c4 + 2] = (f16)hv.z; av[bb][160 + c4 + 3] = (f16)hv.w;
  }
  if (tid < 256) { const int bb = tid >> 4, p = tid & 15; av[bb][16 + p] = (f16)0.f; }
  else if (tid < 288) { const int q = tid - 256; av[q >> 1][158 + (q & 1)] = (f16)0.f; }
  else if (tid < 320) { const int q = tid - 288; av[q >> 1][286 + (q & 1)] = (f16)0.f; }
  if (tid < 16) prevS[tid] = xenc[((size_t)(NT - 1) * NB + b0 + tid) * 20];
  __syncthreads();

  const int m = col, ko = quad * 8;
  for (int s = 0; s < NS; ++s) {
    // p1: Wh = h @ Wl^T + Wlb ; stage head [prev, dec_x]
    {
      f16x8 Ah[4];
#pragma unroll
      for (int kt = 0; kt < 4; ++kt) Ah[kt] = *(const f16x8*)&av[m][160 + kt * 32 + ko];
      f32x4 Cw = {wb, wb, wb, wb};
#pragma unroll
      for (int kt = 0; kt < 4; ++kt)
        Cw = __builtin_amdgcn_mfma_f32_16x16x32_f16(Ah[kt], wlB[kt], Cw, 0, 0, 0);
#pragma unroll
      for (int c = 0; c < 4; ++c) WhS[quad * 4 + c][j] = Cw[c];
    }
    if (tid < 240) { const int bb = tid / 15, e = tid % 15;
      av[bb][1 + e] = (f16)xdec[((size_t)s * NB + b0 + bb) * 15 + e]; }
    else if (tid < 256) av[tid - 240][0] = (f16)prevS[tid - 240];
    __syncthreads();  // B1

    // p2: scores. thread's (b)=sb fixed; 14 rounds over t; 8-lane j-split + shfl reduce
    {
      float wr[16];
#pragma unroll
      for (int i = 0; i < 4; ++i)
        *(float4*)&wr[i * 4] = *(const float4*)&WhS[sb][sub * 16 + i * 4];
      const f16* up0 = uoO + (size_t)(b0 + sb) * NT * 128 + sub * 16;
      const int t4 = g >> 4;
#pragma unroll 2
      for (int rd = 0; rd < 14; ++rd) {
        const int t = rd * 4 + t4;
        const f16* up = up0 + (size_t)t * 128;
        const f16x8 q0 = *(const f16x8*)&up[0];
        const f16x8 q1 = *(const f16x8*)&up[8];
        float acc = 0.f;
#pragma unroll
        for (int i = 0; i < 8; ++i) acc += ftanh((float)q0[i] + wr[i]) * vreg[i];
#pragma unroll
        for (int i = 0; i < 8; ++i) acc += ftanh((float)q1[i] + wr[8 + i]) * vreg[8 + i];
        acc += __shfl_xor(acc, 1, 64);
        acc += __shfl_xor(acc, 2, 64);
        acc += __shfl_xor(acc, 4, 64);
        if (sub == 0) scS[sb][t] = acc + vb0;
      }
    }
    __syncthreads();  // B2

    // p3: per-8-lane-group softmax (redundant 4x per b) + attn accumulation
    {
      const int bb = g & 15, jblk = g >> 4;
      float sv[7], areg[7];
      float mx = -1e30f;
#pragma unroll
      for (int i = 0; i < 7; ++i) { sv[i] = scS[bb][i * 8 + sub]; mx = fmaxf(mx, sv[i]); }
      mx = fmaxf(mx, __shfl_xor(mx, 1, 64));
      mx = fmaxf(mx, __shfl_xor(mx, 2, 64));
      mx = fmaxf(mx, __shfl_xor(mx, 4, 64));
      float zs = 0.f;
#pragma unroll
      for (int i = 0; i < 7; ++i) {
        areg[i] = fexp2(1.4426950408889634f * (sv[i] - mx)); zs += areg[i];
      }
      zs += __shfl_xor(zs, 1, 64);
      zs += __shfl_xor(zs, 2, 64);
      zs += __shfl_xor(zs, 4, 64);
      const float inv = frcp(zs);
#pragma unroll
      for (int i = 0; i < 7; ++i) areg[i] *= inv;

      const int j0 = jblk * 32 + sub * 4;
      const f16* erow = encO + (size_t)(b0 + bb) * NT * 128 + j0;
      const int gbase = l & 56;
      float a0 = 0.f, a1 = 0.f, a2 = 0.f, a3 = 0.f;
#pragma unroll
      for (int t = 0; t < NT; ++t) {
        const float al = __shfl(areg[t >> 3], gbase | (t & 7), 64);
        const f16x4 ev = *(const f16x4*)&erow[(size_t)t * 128];
        a0 += al * (float)ev[0]; a1 += al * (float)ev[1];
        a2 += al * (float)ev[2]; a3 += al * (float)ev[3];
      }
      f16x4 st; st[0] = (f16)a0; st[1] = (f16)a1; st[2] = (f16)a2; st[3] = (f16)a3;
      *(f16x4*)&av[bb][32 + j0] = st;
    }
    __syncthreads();  // B3

    // p4: GRU gates (MFMA) + state update
    {
      f16x8 A[9];
#pragma unroll
      for (int kt = 0; kt < 9; ++kt) A[kt] = *(const f16x8*)&av[m][kt * 32 + ko];
      __syncthreads();  // B4: A-loads complete before h'-writes
      f32x4 Cr = {br, br, br, br}, Cz = {bz, bz, bz, bz};
      f32x4 Cnx = {bnx, bnx, bnx, bnx}, Cnh = {bnh, bnh, bnh, bnh};
#pragma unroll
      for (int kt = 0; kt < 9; ++kt) {
        Cr = __builtin_amdgcn_mfma_f32_16x16x32_f16(A[kt], rB[kt], Cr, 0, 0, 0);
        Cz = __builtin_amdgcn_mfma_f32_16x16x32_f16(A[kt], zB[kt], Cz, 0, 0, 0);
      }
#pragma unroll
      for (int kt = 0; kt < 5; ++kt)
        Cnx = __builtin_amdgcn_mfma_f32_16x16x32_f16(A[kt], nxB[kt], Cnx, 0, 0, 0);
#pragma unroll
      for (int kt = 0; kt < 4; ++kt)
        Cnh = __builtin_amdgcn_mfma_f32_16x16x32_f16(A[kt + 5], nhB[kt], Cnh, 0, 0, 0);
#pragma unroll
      for (int c = 0; c < 4; ++c) {
        const int bb = quad * 4 + c;
        const float hold = (float)av[bb][160 + j];
        const float r = sigm(Cr[c]), z = sigm(Cz[c]);
        const float n = ftanh(Cnx[c] + r * Cnh[c]);
        const float h2 = (1.f - z) * n + z * hold;
        if (valid) av[bb][160 + j] = (f16)h2;
      }
    }
    __syncthreads();  // B5

    // p5: out = h' . h2o + b  (groups 0..15 = waves 0,1)
    if (g < 16) {
      const int bb = g, j0 = sub * 16;
      const f16x8 h0v = *(const f16x8*)&av[bb][160 + j0];
      const f16x8 h1v = *(const f16x8*)&av[bb][160 + j0 + 8];
      float acc = 0.f;
#pragma unroll
      for (int i = 0; i < 8; ++i) acc += (float)h0v[i] * howreg[i];
#pragma unroll
      for (int i = 0; i < 8; ++i) acc += (float)h1v[i] * howreg[8 + i];
      acc += __shfl_xor(acc, 1, 64);
      acc += __shfl_xor(acc, 2, 64);
      acc += __shfl_xor(acc, 4, 64);
      if (sub == 0) {
        const float o = acc + hob0;
        out[(size_t)s * NB + b0 + bb] = o;
        prevS[bb] = o;
      }
    }
    __syncthreads();  // B6 (prev ready for next step)
  }
}

extern "C" void kernel_launch(void* const* d_in, const int* in_sizes, int n_in,
                              void* d_out, int out_size, void* d_ws, size_t ws_size,
                              hipStream_t stream)
{
  const float* ann   = (const float*)d_in[0];
  const float* xenc  = (const float*)d_in[1];
  const float* xdec  = (const float*)d_in[2];
  const float* W1    = (const float*)d_in[3];
  const float* b1    = (const float*)d_in[4];
  const float* W2    = (const float*)d_in[5];
  const float* b2    = (const float*)d_in[6];
  const float* eWih  = (const float*)d_in[7];
  const float* eWhh  = (const float*)d_in[8];
  const float* ebih  = (const float*)d_in[9];
  const float* ebhh  = (const float*)d_in[10];
  const float* dWih  = (const float*)d_in[11];
  const float* dWhh  = (const float*)d_in[12];
  const float* dbih  = (const float*)d_in[13];
  const float* dbhh  = (const float*)d_in[14];
  const float* UW    = (const float*)d_in[15];
  const float* Ubias = (const float*)d_in[16];
  const float* Wl    = (const float*)d_in[17];
  const float* Wlb   = (const float*)d_in[18];
  const float* Vw    = (const float*)d_in[19];
  const float* Vb    = (const float*)d_in[20];
  const float* how   = (const float*)d_in[21];
  const float* hob   = (const float*)d_in[22];

  char* ws = (char*)d_ws;
  float* hstate = (float*)(ws + OFF_H);
  f16*   encB   = (f16*)(ws + OFF_ENC);
  f16*   uoB    = (f16*)(ws + OFF_UO);
  const f16* pWenc = (const f16*)(ws + OFF_WENC);
  const f16* pWdec = (const f16*)(ws + OFF_WDEC);
  const f16* pWl   = (const f16*)(ws + OFF_WL);
  const f16* pUW   = (const f16*)(ws + OFF_UW);

  k_prep<<<200, 256, 0, stream>>>(eWih, eWhh, dWih, dWhh, UW, Wl, ws);
  k_mlp <<<128, 256, 0, stream>>>(ann, W1, b1, W2, b2, hstate);
  k_enc <<<NB / 16, 512, 0, stream>>>(xenc, pWenc, pUW, ebih, ebhh, Ubias,
                                      hstate, encB, uoB);
  k_dec <<<NB / 16, 512, 0, stream>>>(xdec, xenc, pWdec, pWl, dbih, dbhh,
                                      Wlb, Vw, Vb, how, hob, hstate,
                                      encB, uoB, (float*)d_out);
}